// Round 1
// baseline (1316.880 us; speedup 1.0000x reference)
//
#include <hip/hip_runtime.h>
#include <cstdint>

#define B_ 8
#define C_ 128
#define L_ 16
#define G_ 4
#define CPG_ 32
#define H_ 56
#define W_ 56
#define HW_ 3136
#define TH_ 32          // tile rows per block
#define CH_ 8           // channels per LDS chunk
#define NCH_ 4          // 32 / CH_
#define TC_ 64          // tile cols (w = col - 4), cols 0..3 and 60..63 are zero pad

typedef __attribute__((address_space(3))) uint32_t lds_u32;
typedef const __attribute__((address_space(1))) uint32_t glb_u32;

__global__ __launch_bounds__(256, 2)
void wcorr(const float* __restrict__ x, const float* __restrict__ wgt,
           float* __restrict__ out) {
  __shared__ float tile[CH_ * TH_ * TC_];   // 64 KiB

  // bijective chunked XCD swizzle: nwg = 7168 = 8 * 896, dy is fastest in wid
  int bid = blockIdx.x;
  int wid = (bid & 7) * 896 + (bid >> 3);

  int dy = wid % 7;
  int rest = wid / 7;              // ((b*16 + t)*4 + g)*2 + htile
  int htile = rest & 1; rest >>= 1;
  int g = rest & 3;     rest >>= 2;
  int t = rest & 15;
  int b = rest >> 4;

  int tid = threadIdx.x;
  int tx = tid & 7;                // 0..7 (tx==7 idle for compute: w 56..63)
  int ty = tid >> 3;               // 0..31
  int h0 = htile * TH_;
  int h  = h0 + ty;                // output row
  int w0 = tx * 8;                 // first of 8 w positions
  bool active = (tx < 7) && (h < H_);
  int t1 = (t > 0) ? (t - 1) : 0;

  // pre-zero LDS once: pad slots (value-blocks 0 and 15, OOB rows) are never
  // overwritten by staging, so zeros persist across all chunks.
  for (int i = tid; i < CH_ * TH_ * TC_; i += 256) tile[i] = 0.0f;

  float acc[7][8];
  #pragma unroll
  for (int i = 0; i < 7; ++i)
    #pragma unroll
    for (int p = 0; p < 8; ++p) acc[i][p] = 0.0f;

  int wave = tid >> 6;
  int lane = tid & 63;
  int sub  = lane >> 4;            // row-within-call 0..3
  int q    = lane & 15;            // storage 16B-block within row

  __syncthreads();

  const size_t cstride = (size_t)L_ * HW_;             // per-channel stride
  const float* xg = x + ((size_t)b * C_ + (size_t)g * CPG_) * cstride;

  for (int chunk = 0; chunk < NCH_; ++chunk) {
    int c0 = chunk * CH_;
    // ---- stage CH_ channels x TH_ rows x 64 cols via global_load_lds ----
    // LDS dest is linear (base + lane*16); the XOR swizzle (storage block =
    // value block ^ (row&3)) is applied by pre-swizzling the GLOBAL source.
    #pragma unroll
    for (int it = 0; it < 16; ++it) {
      int crow = it * 16 + wave * 4 + sub;   // 0..255
      int ci = crow >> 5;                    // channel within chunk
      int r  = crow & 31;                    // tile row (== reader ty)
      int hh = h0 + r + dy - 3;              // global input row for this dy
      int vb = q ^ (r & 3);                  // value 16B-block this lane carries
      int wq = vb * 4 - 4;                   // w of first float in the block
      bool v = (vb >= 1) && (vb <= 14) && (hh >= 0) && (hh < H_);
      const float* src = xg + (size_t)(c0 + ci) * cstride
                            + (size_t)t * HW_ + hh * W_ + wq;
      float* dst = &tile[(it * 16 + wave * 4) * TC_];  // wave-uniform
      if (v)
        __builtin_amdgcn_global_load_lds((glb_u32*)src, (lds_u32*)dst, 16, 0, 0);
    }
    __syncthreads();   // drains vmcnt(0) -> staged data visible

    if (active) {
      #pragma unroll
      for (int ci = 0; ci < CH_; ++ci) {
        int gch = g * CPG_ + c0 + ci;
        // weights: block-uniform -> scalar loads
        const float* wp = wgt + (size_t)gch * (L_ * 49) + t * 49 + dy * 7;
        float w7[7];
        #pragma unroll
        for (int d = 0; d < 7; ++d) w7[d] = wp[d];
        // x1 = x at t-1 (clamped), this thread's 8 positions, from global (L2-hot)
        const float* x1p = x + ((size_t)b * C_ + gch) * cstride
                             + (size_t)t1 * HW_ + h * W_ + w0;
        float4 a0 = *(const float4*)x1p;
        float4 a1 = *(const float4*)(x1p + 4);
        float x1v[8] = {a0.x, a0.y, a0.z, a0.w, a1.x, a1.y, a1.z, a1.w};
        // xs row: 16 floats, cols [w0, w0+16) in value space, XOR-swizzled storage
        const float4* rb = (const float4*)&tile[(ci * TH_ + ty) * TC_];
        int s = ty & 3;
        int vb0 = 2 * tx;
        float4 q0 = rb[(vb0 + 0) ^ s];
        float4 q1 = rb[(vb0 + 1) ^ s];
        float4 q2 = rb[(vb0 + 2) ^ s];
        float4 q3 = rb[(vb0 + 3) ^ s];
        float rr[16] = {q0.x, q0.y, q0.z, q0.w, q1.x, q1.y, q1.z, q1.w,
                        q2.x, q2.y, q2.z, q2.w, q3.x, q3.y, q3.z, q3.w};
        // position w0+p, offset dx reads value col (w0+p) + dx + 1 -> rr[p+dx+1]
        #pragma unroll
        for (int dxx = 0; dxx < 7; ++dxx) {
          #pragma unroll
          for (int p = 0; p < 8; ++p) {
            acc[dxx][p] = fmaf(w7[dxx], x1v[p] * rr[p + dxx + 1], acc[dxx][p]);
          }
        }
      }
    }
    __syncthreads();   // compute done before next chunk overwrites tile
  }

  if (active) {
    const float sc = 1.0f / 32.0f;
    #pragma unroll
    for (int dxx = 0; dxx < 7; ++dxx) {
      int och = (dy * 7 + dxx) * G_ + g;
      float* op = out + (((size_t)b * 196 + och) * L_ + t) * (size_t)HW_
                      + h * W_ + w0;
      float4 o0 = make_float4(acc[dxx][0] * sc, acc[dxx][1] * sc,
                              acc[dxx][2] * sc, acc[dxx][3] * sc);
      float4 o1 = make_float4(acc[dxx][4] * sc, acc[dxx][5] * sc,
                              acc[dxx][6] * sc, acc[dxx][7] * sc);
      *(float4*)op = o0;
      *(float4*)(op + 4) = o1;
    }
  }
}

extern "C" void kernel_launch(void* const* d_in, const int* in_sizes, int n_in,
                              void* d_out, int out_size, void* d_ws, size_t ws_size,
                              hipStream_t stream) {
  const float* x = (const float*)d_in[0];
  const float* w = (const float*)d_in[1];
  float* o = (float*)d_out;
  dim3 grid(7168), block(256);
  hipLaunchKernelGGL(wcorr, grid, block, 0, stream, x, w, o);
}

// Round 2
// 801.131 us; speedup vs baseline: 1.6438x; 1.6438x over previous
//
#include <hip/hip_runtime.h>
#include <cstdint>

#define C_ 128
#define L_ 16
#define G_ 4
#define CPG_ 32
#define H_ 56
#define W_ 56
#define HW_ 3136

// Block = (b, t, g, htile, dy); 256 threads = 8 tx (w-segments of 8) x 32 ty (rows).
// No LDS: each thread keeps a 16-float sliding window rr[] covering its 8 output
// positions for all 7 dx offsets. All float4 loads are 16B-aligned because w0-4
// is a multiple of 4 and the spatial boundaries (0, 56) are multiples of 4, so
// every 4-float block is either fully valid or fully zero.
__global__ __launch_bounds__(256, 4)
void wcorr(const float* __restrict__ x, const float* __restrict__ wgt,
           float* __restrict__ out) {
  int bid = blockIdx.x;
  // bijective XCD swizzle: nwg = 7168 = 8 * 896; dy varies fastest per XCD so
  // the 7 dy-siblings (which share input rows) run adjacently on one XCD's L2.
  int wid = (bid & 7) * 896 + (bid >> 3);
  int dy = wid % 7;
  int rest = wid / 7;              // ((b*16 + t)*4 + g)*2 + htile
  int htile = rest & 1; rest >>= 1;
  int g = rest & 3;     rest >>= 2;
  int t = rest & 15;
  int b = rest >> 4;

  int tid = threadIdx.x;
  int tx = tid & 7;                // 0..7 (tx==7 duplicates tx==6's segment, store-masked)
  int ty = tid >> 3;               // 0..31
  int h = htile * 32 + ty;
  if (h >= H_) return;             // wave-uniform (only htile=1, ty>=24 wave exits)

  bool wr = (tx < 7);
  int w0 = wr ? tx * 8 : 48;       // clamp inactive lanes to a safe in-bounds segment
  int hh = h + dy - 3;
  bool hv = (hh >= 0) && (hh < H_);
  int hhs = hv ? hh : 0;
  int t1 = (t > 0) ? (t - 1) : 0;

  // validity of the four 4-float blocks at value cols w0-4, w0, w0+4, w0+8
  bool m0 = hv && (w0 >= 4);
  bool m1 = hv;
  bool m2 = hv;                    // w0+4 <= 52 < 56 always
  bool m3 = hv && (w0 + 8 < W_);

  const size_t cstride = (size_t)L_ * HW_;
  const float* xbase = x + ((size_t)b * C_ + (size_t)g * CPG_) * cstride;
  const float* xs0 = xbase + (size_t)t * HW_ + (size_t)hhs * W_ + (w0 - 4);
  const float* x10 = xbase + (size_t)t1 * HW_ + (size_t)h * W_ + w0;
  const float* wg0 = wgt + (size_t)(g * CPG_) * (L_ * 49) + t * 49 + dy * 7;

  float acc[7][8];
  #pragma unroll
  for (int i = 0; i < 7; ++i)
    #pragma unroll
    for (int p = 0; p < 8; ++p) acc[i][p] = 0.0f;

  #pragma unroll 4
  for (int c = 0; c < CPG_; ++c) {
    // weights: wave-uniform addresses -> scalar loads
    const float* wp = wg0 + (size_t)c * (L_ * 49);
    float w7[7];
    #pragma unroll
    for (int d = 0; d < 7; ++d) w7[d] = wp[d];

    const float* xs = xs0 + (size_t)c * cstride;
    float4 q0 = make_float4(0.f, 0.f, 0.f, 0.f);
    float4 q1 = q0, q2 = q0, q3 = q0;
    if (m0) q0 = *(const float4*)(xs);
    if (m1) q1 = *(const float4*)(xs + 4);
    if (m2) q2 = *(const float4*)(xs + 8);
    if (m3) q3 = *(const float4*)(xs + 12);

    const float* x1p = x10 + (size_t)c * cstride;
    float4 a0 = *(const float4*)(x1p);
    float4 a1 = *(const float4*)(x1p + 4);

    float rr[16] = {q0.x, q0.y, q0.z, q0.w, q1.x, q1.y, q1.z, q1.w,
                    q2.x, q2.y, q2.z, q2.w, q3.x, q3.y, q3.z, q3.w};
    float x1v[8] = {a0.x, a0.y, a0.z, a0.w, a1.x, a1.y, a1.z, a1.w};

    // output position w0+p, offset dx reads value col (w0+p)+dx-3 -> rr[p+dx+1]
    #pragma unroll
    for (int dxx = 0; dxx < 7; ++dxx) {
      #pragma unroll
      for (int p = 0; p < 8; ++p) {
        acc[dxx][p] = fmaf(w7[dxx], x1v[p] * rr[p + dxx + 1], acc[dxx][p]);
      }
    }
  }

  if (wr) {
    const float sc = 1.0f / 32.0f;
    #pragma unroll
    for (int dxx = 0; dxx < 7; ++dxx) {
      int och = (dy * 7 + dxx) * G_ + g;
      float* op = out + (((size_t)b * 196 + och) * L_ + t) * (size_t)HW_
                      + (size_t)h * W_ + w0;
      float4 o0 = make_float4(acc[dxx][0] * sc, acc[dxx][1] * sc,
                              acc[dxx][2] * sc, acc[dxx][3] * sc);
      float4 o1 = make_float4(acc[dxx][4] * sc, acc[dxx][5] * sc,
                              acc[dxx][6] * sc, acc[dxx][7] * sc);
      *(float4*)op = o0;
      *(float4*)(op + 4) = o1;
    }
  }
}

extern "C" void kernel_launch(void* const* d_in, const int* in_sizes, int n_in,
                              void* d_out, int out_size, void* d_ws, size_t ws_size,
                              hipStream_t stream) {
  const float* x = (const float*)d_in[0];
  const float* w = (const float*)d_in[1];
  float* o = (float*)d_out;
  dim3 grid(7168), block(256);
  hipLaunchKernelGGL(wcorr, grid, block, 0, stream, x, w, o);
}

// Round 3
// 455.353 us; speedup vs baseline: 2.8920x; 1.7594x over previous
//
#include <hip/hip_runtime.h>
#include <cstdint>

#define C_ 128
#define L_ 16
#define G_ 4
#define CPG_ 32
#define H_ 56
#define W_ 56
#define HW_ 3136

// One block family computes dx in [DX0, DX0+DXN). Window r[12] covers value
// cols [w0+XOFF, w0+XOFF+12); index for (p,di) is p+di+1 in both arms.
// All float4 loads 16B-aligned; spatial pad boundaries are multiples of 4 so
// every 4-block is fully valid or fully zero (masked).
template<int DX0, int DXN>
__device__ __forceinline__ void half_body(
    const float* __restrict__ x, const float* __restrict__ wgt,
    float* __restrict__ out,
    int b, int t, int g, int dy, int h, int w0, bool wr)
{
  constexpr int XOFF = (DX0 == 0) ? -4 : 0;
  int hh = h + dy - 3;
  bool hv = (hh >= 0) && (hh < H_);
  int hhs = hv ? hh : 0;
  int t1 = (t > 0) ? (t - 1) : 0;
  int cb = w0 + XOFF;                 // first loaded value col
  bool m0 = hv && (cb >= 0);          // block at cb
  bool m1 = hv;                       // block at cb+4 (always in [0,52])
  bool m2 = hv && (cb + 8 < W_);      // block at cb+8

  const size_t cstride = (size_t)L_ * HW_;
  const float* xbase = x + ((size_t)b * C_ + (size_t)g * CPG_) * cstride;
  const float* xs0 = xbase + (size_t)t * HW_ + (size_t)hhs * W_ + cb;
  const float* x10 = xbase + (size_t)t1 * HW_ + (size_t)h * W_ + w0;
  const float* wg0 = wgt + (size_t)(g * CPG_) * (L_ * 49) + t * 49 + dy * 7 + DX0;

  float acc[DXN][8];
  #pragma unroll
  for (int i = 0; i < DXN; ++i)
    #pragma unroll
    for (int p = 0; p < 8; ++p) acc[i][p] = 0.0f;

  #pragma unroll 1
  for (int c = 0; c < CPG_; ++c) {
    const float* wp = wg0 + (size_t)c * (L_ * 49);   // wave-uniform -> s_load
    float w7[DXN];
    #pragma unroll
    for (int d = 0; d < DXN; ++d) w7[d] = wp[d];

    const float* xs = xs0 + (size_t)c * cstride;
    float4 q0 = make_float4(0.f, 0.f, 0.f, 0.f);
    float4 q1 = q0, q2 = q0;
    if (m0) q0 = *(const float4*)(xs);
    if (m1) q1 = *(const float4*)(xs + 4);
    if (m2) q2 = *(const float4*)(xs + 8);

    const float* x1p = x10 + (size_t)c * cstride;
    float4 a0 = *(const float4*)(x1p);
    float4 a1 = *(const float4*)(x1p + 4);

    float r[12] = {q0.x, q0.y, q0.z, q0.w, q1.x, q1.y, q1.z, q1.w,
                   q2.x, q2.y, q2.z, q2.w};
    float x1v[8] = {a0.x, a0.y, a0.z, a0.w, a1.x, a1.y, a1.z, a1.w};

    #pragma unroll
    for (int di = 0; di < DXN; ++di) {
      #pragma unroll
      for (int p = 0; p < 8; ++p) {
        // value col w0+p+(DX0+di)-3 -> r[p + DX0 + di - 3 - XOFF] == r[p+di+1]
        acc[di][p] = fmaf(w7[di], x1v[p] * r[p + DX0 + di - 3 - XOFF],
                          acc[di][p]);
      }
    }
  }

  if (wr) {
    const float sc = 1.0f / 32.0f;
    #pragma unroll
    for (int di = 0; di < DXN; ++di) {
      int och = (dy * 7 + DX0 + di) * G_ + g;
      float* op = out + (((size_t)b * 196 + och) * L_ + t) * (size_t)HW_
                      + (size_t)h * W_ + w0;
      float4 o0 = make_float4(acc[di][0] * sc, acc[di][1] * sc,
                              acc[di][2] * sc, acc[di][3] * sc);
      float4 o1 = make_float4(acc[di][4] * sc, acc[di][5] * sc,
                              acc[di][6] * sc, acc[di][7] * sc);
      *(float4*)op = o0;
      *(float4*)(op + 4) = o1;
    }
  }
}

__global__ __launch_bounds__(256)
__attribute__((amdgpu_waves_per_eu(5, 6)))
void wcorr(const float* __restrict__ x, const float* __restrict__ wgt,
           float* __restrict__ out) {
  int bid = blockIdx.x;
  // bijective XCD swizzle: nwg = 14336 = 8 * 1792; dx-half is fastest, then dy,
  // so the 14 blocks sharing one (b,t,g,htile)'s input rows land on one XCD.
  int wid = (bid & 7) * 1792 + (bid >> 3);
  int dh = wid & 1;
  int dy = (wid >> 1) % 7;
  int rest = (wid >> 1) / 7;        // ((b*16 + t)*4 + g)*2 + htile
  int htile = rest & 1; rest >>= 1;
  int g = rest & 3;     rest >>= 2;
  int t = rest & 15;
  int b = rest >> 4;

  int tid = threadIdx.x;
  int tx = tid & 7;                 // 0..7 (tx==7 compute-duplicated, store-masked)
  int ty = tid >> 3;                // 0..31
  int h = htile * 32 + ty;
  if (h >= H_) return;              // whole-wave exit (htile=1, wave 3)
  bool wr = (tx < 7);
  int w0 = wr ? tx * 8 : 48;        // clamp idle lanes to a safe segment

  if (dh == 0)
    half_body<0, 4>(x, wgt, out, b, t, g, dy, h, w0, wr);
  else
    half_body<4, 3>(x, wgt, out, b, t, g, dy, h, w0, wr);
}

extern "C" void kernel_launch(void* const* d_in, const int* in_sizes, int n_in,
                              void* d_out, int out_size, void* d_ws, size_t ws_size,
                              hipStream_t stream) {
  const float* x = (const float*)d_in[0];
  const float* w = (const float*)d_in[1];
  float* o = (float*)d_out;
  dim3 grid(14336), block(256);
  hipLaunchKernelGGL(wcorr, grid, block, 0, stream, x, w, o);
}

// Round 4
// 370.376 us; speedup vs baseline: 3.5555x; 1.2294x over previous
//
#include <hip/hip_runtime.h>
#include <cstdint>

#define C_ 128
#define L_ 16
#define G_ 4
#define CPG_ 32
#define H_ 56
#define W_ 56
#define HW_ 3136

// Block = (b, t, g, htile, dy); 256 threads = 8 tx (w-segments of 8) x 32 ty.
// All 7 dx in-register: acc[7][8]. Window r[16] covers value cols
// [w0-4, w0+12); (p,dx) reads r[p+dx+1]. All float4 loads 16B-aligned; the
// spatial boundaries (0, 56) are multiples of 4 so each 4-float block is
// fully valid or fully zero (masked).
// amdgpu_waves_per_eu(4,4): VGPR budget 128, and max=4 disables the
// shrink-for-occupancy heuristic that serialized loads (r3) / spilled (r2).
__global__ __launch_bounds__(256)
__attribute__((amdgpu_waves_per_eu(4, 4)))
void wcorr(const float* __restrict__ x, const float* __restrict__ wgt,
           float* __restrict__ out) {
  int bid = blockIdx.x;
  // bijective XCD swizzle: nwg = 7168 = 8 * 896; dy fastest so the 7
  // dy-siblings sharing input rows run adjacently on one XCD's L2.
  int wid = (bid & 7) * 896 + (bid >> 3);
  int dy = wid % 7;
  int rest = wid / 7;              // ((b*16 + t)*4 + g)*2 + htile
  int htile = rest & 1; rest >>= 1;
  int g = rest & 3;     rest >>= 2;
  int t = rest & 15;
  int b = rest >> 4;

  int tid = threadIdx.x;
  int tx = tid & 7;                // 0..7 (tx==7 compute-duplicated, store-masked)
  int ty = tid >> 3;               // 0..31
  int h = htile * 32 + ty;
  if (h >= H_) return;             // whole-wave exit (htile=1, wave 3)

  bool wr = (tx < 7);
  int w0 = wr ? tx * 8 : 48;       // clamp idle lanes to a safe segment
  int hh = h + dy - 3;
  bool hv = (hh >= 0) && (hh < H_);
  int hhs = hv ? hh : 0;
  int t1 = (t > 0) ? (t - 1) : 0;

  // validity of the four 4-col blocks at value cols w0-4, w0, w0+4, w0+8
  bool m0 = hv && (w0 >= 4);
  bool m1 = hv;
  bool m2 = hv;                    // w0+4 <= 52 always in-bounds
  bool m3 = hv && (w0 + 8 < W_);

  const size_t cstride = (size_t)L_ * HW_;
  const float* xbase = x + ((size_t)b * C_ + (size_t)g * CPG_) * cstride;
  const float* xs0 = xbase + (size_t)t * HW_ + (size_t)hhs * W_ + (w0 - 4);
  const float* x10 = xbase + (size_t)t1 * HW_ + (size_t)h * W_ + w0;
  const float* wg0 = wgt + (size_t)(g * CPG_) * (L_ * 49) + t * 49 + dy * 7;

  float acc[7][8];
  #pragma unroll
  for (int i = 0; i < 7; ++i)
    #pragma unroll
    for (int p = 0; p < 8; ++p) acc[i][p] = 0.0f;

  #pragma unroll 2
  for (int c = 0; c < CPG_; ++c) {
    // issue all global loads first, then the (wave-uniform -> s_load) weights
    const float* xs = xs0 + (size_t)c * cstride;
    const float* x1p = x10 + (size_t)c * cstride;
    float4 q0 = make_float4(0.f, 0.f, 0.f, 0.f);
    float4 q1 = q0, q2 = q0, q3 = q0;
    if (m0) q0 = *(const float4*)(xs);
    if (m1) q1 = *(const float4*)(xs + 4);
    if (m2) q2 = *(const float4*)(xs + 8);
    if (m3) q3 = *(const float4*)(xs + 12);
    float4 a0 = *(const float4*)(x1p);
    float4 a1 = *(const float4*)(x1p + 4);

    const float* wp = wg0 + (size_t)c * (L_ * 49);
    float w7[7];
    #pragma unroll
    for (int d = 0; d < 7; ++d) w7[d] = wp[d];

    float r[16] = {q0.x, q0.y, q0.z, q0.w, q1.x, q1.y, q1.z, q1.w,
                   q2.x, q2.y, q2.z, q2.w, q3.x, q3.y, q3.z, q3.w};
    float x1v[8] = {a0.x, a0.y, a0.z, a0.w, a1.x, a1.y, a1.z, a1.w};

    // output position w0+p, offset dx reads value col (w0+p)+dx-3 -> r[p+dx+1]
    #pragma unroll
    for (int dxx = 0; dxx < 7; ++dxx) {
      #pragma unroll
      for (int p = 0; p < 8; ++p) {
        acc[dxx][p] = fmaf(w7[dxx], x1v[p] * r[p + dxx + 1], acc[dxx][p]);
      }
    }
  }

  if (wr) {
    const float sc = 1.0f / 32.0f;
    #pragma unroll
    for (int dxx = 0; dxx < 7; ++dxx) {
      int och = (dy * 7 + dxx) * G_ + g;
      float* op = out + (((size_t)b * 196 + och) * L_ + t) * (size_t)HW_
                      + (size_t)h * W_ + w0;
      float4 o0 = make_float4(acc[dxx][0] * sc, acc[dxx][1] * sc,
                              acc[dxx][2] * sc, acc[dxx][3] * sc);
      float4 o1 = make_float4(acc[dxx][4] * sc, acc[dxx][5] * sc,
                              acc[dxx][6] * sc, acc[dxx][7] * sc);
      *(float4*)op = o0;
      *(float4*)(op + 4) = o1;
    }
  }
}

extern "C" void kernel_launch(void* const* d_in, const int* in_sizes, int n_in,
                              void* d_out, int out_size, void* d_ws, size_t ws_size,
                              hipStream_t stream) {
  const float* x = (const float*)d_in[0];
  const float* w = (const float*)d_in[1];
  float* o = (float*)d_out;
  dim3 grid(7168), block(256);
  hipLaunchKernelGGL(wcorr, grid, block, 0, stream, x, w, o);
}